// Round 1
// baseline (6536.217 us; speedup 1.0000x reference)
//
#include <hip/hip_runtime.h>
#include <cstddef>

static constexpr int Nn   = 16000;
static constexpr int Fdim = 500;
static constexpr int Hdim = 256;
static constexpr int Cdim = 64;
static constexpr int Din  = Fdim + 3 * Hdim;   // 1268
static constexpr int Din4 = Din / 4;           // 317

// ---------------- helpers ----------------
__device__ __forceinline__ float geluf(float v) {
    return 0.5f * v * (1.f + erff(v * 0.70710678118654752440f));
}
__device__ __forceinline__ float siluf(float v) {
    return v / (1.f + expf(-v));
}
__device__ __forceinline__ void atomAddF(float* p, float v) {
    unsafeAtomicAdd(p, v);   // native global_atomic_add_f32 on gfx950
}

// Cox-de Boor cubic B-splines on uniform grid t_i = -2.5 + 0.5*i (i=0..10) -> 7 bases
__device__ __forceinline__ void bsplines7(float z, float* B) {
    float b[10];
#pragma unroll
    for (int i = 0; i < 10; i++) {
        const float t0 = 0.5f * i - 2.5f;
        b[i] = (z >= t0 && z < t0 + 0.5f) ? 1.f : 0.f;
    }
#pragma unroll
    for (int j = 1; j <= 3; j++) {
        const float inv = 2.0f / (float)j;   // 1/(0.5*j)
#pragma unroll
        for (int i = 0; i < 10 - j; i++) {
            const float ti = 0.5f * i - 2.5f;
            b[i] = (z - ti) * inv * b[i] + ((ti + 0.5f * (j + 1)) - z) * inv * b[i + 1];
        }
    }
#pragma unroll
    for (int g = 0; g < 7; g++) B[g] = b[g];
}

// ---------------- GEMM: C = A @ W^T + bias (optional exact GELU) ----------------
// A [M,K] lda, W [Nout,K] ldw, C [M,Nout] ldc. 128x128 tile, BK=16, 8x8/thread.
template <int ACT>
__global__ __launch_bounds__(256, 2) void gemm_nt(
    const float* __restrict__ A, int lda,
    const float* __restrict__ W, int ldw,
    const float* __restrict__ bias,
    float* __restrict__ Co, int ldc,
    int M, int Nout, int K)
{
    __shared__ __align__(16) float As[4][130][4];   // [k4][m][kr], k4-stride padded (130*4)
    __shared__ __align__(16) float Bs[4][130][4];

    const int tid = threadIdx.x;
    const int tx = tid & 15, ty = tid >> 4;
    const int bm = blockIdx.x * 128;
    const int bn = blockIdx.y * 128;

    float acc[8][8];
#pragma unroll
    for (int r = 0; r < 8; r++)
#pragma unroll
        for (int c = 0; c < 8; c++) acc[r][c] = 0.f;

    const int lk4 = tid & 3;       // which 4-k group
    const int lrow = tid >> 2;     // 0..63

    for (int kt = 0; kt < K; kt += 16) {
        const int col = kt + lk4 * 4;
#pragma unroll
        for (int h = 0; h < 2; h++) {
            const int row = lrow + 64 * h;
            float4 v = make_float4(0.f, 0.f, 0.f, 0.f);
            const size_t abase = (size_t)(bm + row) * lda;
            if (col + 3 < K) {
                v = *(const float4*)(A + abase + col);
            } else {
                if (col + 0 < K) v.x = A[abase + col + 0];
                if (col + 1 < K) v.y = A[abase + col + 1];
                if (col + 2 < K) v.z = A[abase + col + 2];
            }
            *(float4*)(&As[lk4][row][0]) = v;

            float4 w = make_float4(0.f, 0.f, 0.f, 0.f);
            const int wr = bn + row;
            if (wr < Nout) {
                const size_t wbase = (size_t)wr * ldw;
                if (col + 3 < K) {
                    w = *(const float4*)(W + wbase + col);
                } else {
                    if (col + 0 < K) w.x = W[wbase + col + 0];
                    if (col + 1 < K) w.y = W[wbase + col + 1];
                    if (col + 2 < K) w.z = W[wbase + col + 2];
                }
            }
            *(float4*)(&Bs[lk4][row][0]) = w;
        }
        __syncthreads();
#pragma unroll
        for (int k4 = 0; k4 < 4; k4++) {
            float4 a[8], b[8];
#pragma unroll
            for (int r = 0; r < 8; r++) a[r] = *(const float4*)(&As[k4][ty + 16 * r][0]);
#pragma unroll
            for (int c = 0; c < 8; c++) b[c] = *(const float4*)(&Bs[k4][tx + 16 * c][0]);
#pragma unroll
            for (int r = 0; r < 8; r++)
#pragma unroll
                for (int c = 0; c < 8; c++) {
                    acc[r][c] += a[r].x * b[c].x;
                    acc[r][c] += a[r].y * b[c].y;
                    acc[r][c] += a[r].z * b[c].z;
                    acc[r][c] += a[r].w * b[c].w;
                }
        }
        __syncthreads();
    }

#pragma unroll
    for (int r = 0; r < 8; r++) {
        const int m = bm + ty + 16 * r;   // always < M (M = 16000 = 125*128)
#pragma unroll
        for (int c = 0; c < 8; c++) {
            const int n = bn + tx + 16 * c;
            if (n < Nout) {
                float v = acc[r][c] + bias[n];
                if (ACT == 1) v = geluf(v);
                Co[(size_t)m * ldc + n] = v;
            }
        }
    }
}

// ---------------- graph pieces ----------------
__global__ void copy_x_kernel(const float* __restrict__ x, float* __restrict__ hcat) {
    const int total = Nn * (Fdim / 4);   // 2,000,000 float4
    for (int i = blockIdx.x * blockDim.x + threadIdx.x; i < total; i += gridDim.x * blockDim.x) {
        const int row = i / (Fdim / 4), c4 = i % (Fdim / 4);
        ((float4*)hcat)[(size_t)row * Din4 + c4] = ((const float4*)x)[i];
    }
}
__global__ void deg_init(float* deg) {
    int i = blockIdx.x * blockDim.x + threadIdx.x;
    if (i < Nn) deg[i] = 1.f;   // self loop
}
__global__ void deg_edges(const int* __restrict__ ei, float* deg, int E) {
    for (int e = blockIdx.x * blockDim.x + threadIdx.x; e < E; e += gridDim.x * blockDim.x)
        atomAddF(&deg[ei[E + e]], 1.f);
}
__global__ void deg_finish(float* deg) {
    int i = blockIdx.x * blockDim.x + threadIdx.x;
    if (i < Nn) deg[i] = 1.f / sqrtf(deg[i]);
}
__global__ void agg_init(const float* __restrict__ cb, float* __restrict__ agg) {
    const int total = Nn * (Hdim / 4);
    const float4* c4 = (const float4*)cb;
    for (int i = blockIdx.x * blockDim.x + threadIdx.x; i < total; i += gridDim.x * blockDim.x)
        ((float4*)agg)[i] = c4[i & 63];
}
// one wave per edge; 64 lanes x float4 = 256 channels
__global__ void scatter_add(const float* __restrict__ z, const int* __restrict__ ei,
                            const float* __restrict__ dinv, float* __restrict__ agg, int E) {
    const int lane = threadIdx.x & 63;
    const int wid = (blockIdx.x * blockDim.x + threadIdx.x) >> 6;
    const int nw = (gridDim.x * blockDim.x) >> 6;
    const int total = E + Nn;
    for (int e = wid; e < total; e += nw) {
        int s, d;
        if (e < E) { s = ei[e]; d = ei[E + e]; }
        else { s = e - E; d = s; }
        const float w = dinv[s] * dinv[d];
        const float4 v = *(const float4*)(z + (size_t)s * Hdim + lane * 4);
        float* a = agg + (size_t)d * Hdim + lane * 4;
        atomAddF(a + 0, v.x * w);
        atomAddF(a + 1, v.y * w);
        atomAddF(a + 2, v.z * w);
        atomAddF(a + 3, v.w * w);
    }
}
__global__ void bn_stats(const float* __restrict__ agg, float* __restrict__ stats) {
    const int col = threadIdx.x;
    const int r0 = blockIdx.x * 128;
    float s = 0.f, q = 0.f;
    for (int r = 0; r < 128; r++) {
        const float v = agg[(size_t)(r0 + r) * Hdim + col];
        s += v; q += v * v;
    }
    atomAddF(&stats[col], s);
    atomAddF(&stats[Hdim + col], q);
}
__global__ void bn_final(const float* __restrict__ stats, const float* __restrict__ g,
                         const float* __restrict__ b, float* __restrict__ sc, float* __restrict__ sh) {
    const int c = threadIdx.x;
    const float mu = stats[c] * (1.f / Nn);
    const float var = stats[Hdim + c] * (1.f / Nn) - mu * mu;
    const float rs = 1.f / sqrtf(var + 1e-5f);
    const float scale = rs * g[c];
    sc[c] = scale;
    sh[c] = b[c] - mu * scale;
}
__global__ void bn_apply(const float* __restrict__ agg, const float* __restrict__ sc,
                         const float* __restrict__ sh, float* __restrict__ hcat, int c4off) {
    const int total = Nn * (Hdim / 4);
    for (int i = blockIdx.x * blockDim.x + threadIdx.x; i < total; i += gridDim.x * blockDim.x) {
        const int row = i >> 6, c = i & 63;
        const float4 a = ((const float4*)agg)[i];
        const float4 s = ((const float4*)sc)[c];
        const float4 t = ((const float4*)sh)[c];
        float4 v;
        v.x = a.x * s.x + t.x; v.y = a.y * s.y + t.y;
        v.z = a.z * s.z + t.z; v.w = a.w * s.w + t.w;
        ((float4*)hcat)[(size_t)row * Din4 + c4off + c] = v;
    }
}

// ---------------- fused KAN head: silu base + cubic B-spline einsum ----------------
// block: 32 rows x all 64 outputs; BK=16 inputs per chunk
__global__ __launch_bounds__(256, 2) void kan_head(
    const float* __restrict__ hcat, const float* __restrict__ base_w,
    const float* __restrict__ spline_w, float* __restrict__ out)
{
    __shared__ __align__(16) float sb[32 * 17];        // silu values  [m][kk]
    __shared__ __align__(16) float basesS[32 * 132];   // bases [m][kk][8], m-stride 132
    __shared__ __align__(16) float bwS[64 * 17];       // base_w chunk [o][kk]
    __shared__ __align__(16) float swS[64 * 132];      // spline_w chunk [o][kk][8]

    const int tid = threadIdx.x;
    const int tx = tid & 15, ty = tid >> 4;
    const int brow = blockIdx.x * 32;

    float acc[2][4];
#pragma unroll
    for (int r = 0; r < 2; r++)
#pragma unroll
        for (int c = 0; c < 4; c++) acc[r][c] = 0.f;

    for (int i0 = 0; i0 < Din; i0 += 16) {
        const int kw = (Din - i0 < 16) ? (Din - i0) : 16;

        // stage: silu + bases for 32x16 activations
        for (int t = tid; t < 32 * 16; t += 256) {
            const int m = t >> 4, kk = t & 15;
            float s = 0.f;
            float bv[7] = {0.f, 0.f, 0.f, 0.f, 0.f, 0.f, 0.f};
            if (kk < kw) {
                const float z = hcat[(size_t)(brow + m) * Din + i0 + kk];
                bsplines7(z, bv);
                s = siluf(z);
            }
            sb[m * 17 + kk] = s;
            float* d = &basesS[m * 132 + kk * 8];
#pragma unroll
            for (int j = 0; j < 7; j++) d[j] = bv[j];
            d[7] = 0.f;
        }
        // stage weights
        for (int t = tid; t < 64 * 16; t += 256) {
            const int o = t >> 4, kk = t & 15;
            bwS[o * 17 + kk] = (kk < kw) ? base_w[(size_t)o * Din + i0 + kk] : 0.f;
        }
        for (int t = tid; t < 64 * 112; t += 256) {
            const int o = t / 112, r2 = t % 112, kk = r2 / 7, j = r2 % 7;
            swS[o * 132 + kk * 8 + j] = (kk < kw) ? spline_w[((size_t)o * Din + i0 + kk) * 7 + j] : 0.f;
        }
        __syncthreads();

#pragma unroll 4
        for (int kk = 0; kk < 16; kk++) {
            const float s0 = sb[ty * 17 + kk];
            const float s1 = sb[(ty + 16) * 17 + kk];
            const float4 b0a = *(const float4*)&basesS[ty * 132 + kk * 8];
            const float4 b0b = *(const float4*)&basesS[ty * 132 + kk * 8 + 4];
            const float4 b1a = *(const float4*)&basesS[(ty + 16) * 132 + kk * 8];
            const float4 b1b = *(const float4*)&basesS[(ty + 16) * 132 + kk * 8 + 4];
#pragma unroll
            for (int c = 0; c < 4; c++) {
                const int o = tx + 16 * c;
                const float bw = bwS[o * 17 + kk];
                const float4 wa = *(const float4*)&swS[o * 132 + kk * 8];
                const float4 wb = *(const float4*)&swS[o * 132 + kk * 8 + 4];
                acc[0][c] += s0 * bw + b0a.x * wa.x + b0a.y * wa.y + b0a.z * wa.z + b0a.w * wa.w
                           + b0b.x * wb.x + b0b.y * wb.y + b0b.z * wb.z;
                acc[1][c] += s1 * bw + b1a.x * wa.x + b1a.y * wa.y + b1a.z * wa.z + b1a.w * wa.w
                           + b1b.x * wb.x + b1b.y * wb.y + b1b.z * wb.z;
            }
        }
        __syncthreads();
    }

#pragma unroll
    for (int r = 0; r < 2; r++)
#pragma unroll
        for (int c = 0; c < 4; c++)
            out[(size_t)(brow + ty + 16 * r) * Cdim + tx + 16 * c] = acc[r][c];
}

// ---------------- launch ----------------
extern "C" void kernel_launch(void* const* d_in, const int* in_sizes, int n_in,
                              void* d_out, int out_size, void* d_ws, size_t ws_size,
                              hipStream_t stream)
{
    const float* x = (const float*)d_in[0];
    const float *fc1w[3], *fc1b[3], *fc2w[3], *fc2b[3], *cb[3], *bg[3], *bb[3];
    for (int l = 0; l < 3; l++) {
        const int base = 1 + l * 7;
        fc1w[l] = (const float*)d_in[base + 0];
        fc1b[l] = (const float*)d_in[base + 1];
        fc2w[l] = (const float*)d_in[base + 2];
        fc2b[l] = (const float*)d_in[base + 3];
        cb[l]   = (const float*)d_in[base + 4];
        bg[l]   = (const float*)d_in[base + 5];
        bb[l]   = (const float*)d_in[base + 6];
    }
    const float* base_w   = (const float*)d_in[22];
    const float* spline_w = (const float*)d_in[23];
    const int*   ei       = (const int*)d_in[24];
    const int    E        = in_sizes[24] / 2;
    float*       out      = (float*)d_out;

    // workspace layout (floats)
    float* ws    = (float*)d_ws;
    float* hcat  = ws;                                  // N*1268
    float* tbuf  = hcat + (size_t)Nn * Din;             // N*500
    float* zbuf  = tbuf + (size_t)Nn * Fdim;            // N*256
    float* agg   = zbuf + (size_t)Nn * Hdim;            // N*256
    float* dinv  = agg  + (size_t)Nn * Hdim;            // N
    float* stats = dinv + Nn;                           // 512
    float* bnsc  = stats + 512;                         // 256
    float* bnsh  = bnsc + 256;                          // 256
    const size_t needBytes = ((size_t)Nn * Din + (size_t)Nn * Fdim + 2 * (size_t)Nn * Hdim
                              + Nn + 512 + 512) * sizeof(float);
    if (ws_size < needBytes) return;   // insufficient scratch; fail loudly via mismatch

    const dim3 blk(256);
    copy_x_kernel<<<2048, blk, 0, stream>>>(x, hcat);
    deg_init<<<(Nn + 255) / 256, blk, 0, stream>>>(dinv);
    deg_edges<<<1024, blk, 0, stream>>>(ei, dinv, E);
    deg_finish<<<(Nn + 255) / 256, blk, 0, stream>>>(dinv);

    for (int l = 0; l < 3; l++) {
        const int fin = (l == 0) ? Fdim : Hdim;
        const float* Ain = (l == 0) ? hcat : (hcat + Fdim + (size_t)(l - 1) * Hdim);

        dim3 g1(Nn / 128, (fin + 127) / 128);
        gemm_nt<1><<<g1, blk, 0, stream>>>(Ain, Din, fc1w[l], fin, fc1b[l], tbuf, fin, Nn, fin, fin);

        dim3 g2(Nn / 128, (Hdim + 127) / 128);
        gemm_nt<0><<<g2, blk, 0, stream>>>(tbuf, fin, fc2w[l], fin, fc2b[l], zbuf, Hdim, Nn, Hdim, fin);

        agg_init<<<2048, blk, 0, stream>>>(cb[l], agg);
        scatter_add<<<2048, blk, 0, stream>>>(zbuf, ei, dinv, agg, E);

        hipMemsetAsync(stats, 0, 512 * sizeof(float), stream);
        bn_stats<<<125, blk, 0, stream>>>(agg, stats);
        bn_final<<<1, blk, 0, stream>>>(stats, bg[l], bb[l], bnsc, bnsh);
        bn_apply<<<2048, blk, 0, stream>>>(agg, bnsc, bnsh, hcat, (Fdim / 4) + l * (Hdim / 4));
    }

    kan_head<<<Nn / 32, blk, 0, stream>>>(hcat, base_w, spline_w, out);
}

// Round 9
// 4798.202 us; speedup vs baseline: 1.3622x; 1.3622x over previous
//
#include <hip/hip_runtime.h>
#include <cstddef>
#include <cstdint>

typedef unsigned short ushort_t;
typedef __attribute__((ext_vector_type(8))) short bf16x8;
typedef __attribute__((ext_vector_type(4))) float f32x4;

static constexpr int Nn   = 16000;
static constexpr int Mpad = 16128;   // 126*128
static constexpr int Fdim = 500;
static constexpr int Hdim = 256;
static constexpr int Cdim = 64;
static constexpr int HF   = 768;     // hfeat cols (3*256)
static constexpr int KPK  = 10176;   // kan expanded K padded (159*64)

// ---------------- scalar helpers ----------------
__device__ __forceinline__ float geluf(float v) {
    return 0.5f * v * (1.f + erff(v * 0.70710678118654752440f));
}
__device__ __forceinline__ float siluf(float v) {
    return v / (1.f + expf(-v));
}
__device__ __forceinline__ void atomAddF(float* p, float v) { unsafeAtomicAdd(p, v); }

__device__ __forceinline__ ushort_t f2bf(float x) {
    uint32_t u = __float_as_uint(x);
    uint32_t r = (u + 0x7fffu + ((u >> 16) & 1u)) >> 16;
    return (ushort_t)r;
}
__device__ __forceinline__ float bf2f(ushort_t b) {
    return __uint_as_float(((uint32_t)b) << 16);
}

// cubic B-splines, uniform knots t_i = 0.5 i - 2.5 (i=0..10, ELEVEN knots) -> 7 bases.
// ROOT CAUSE of rounds 2/3/8: a rewrite used float d[10] but the recurrence needs
// d[i+j+1] up to index 10 (11 knots) -> OOB read corrupted basis B6 for z in (1, 2.5].
// This is round-1's PROVEN index-free implementation (upper knot computed arithmetically).
__device__ __forceinline__ void bspl7(float z, float* B) {
    float b[10];
#pragma unroll
    for (int i = 0; i < 10; i++) {
        const float t0 = 0.5f * i - 2.5f;
        b[i] = (z >= t0 && z < t0 + 0.5f) ? 1.f : 0.f;
    }
#pragma unroll
    for (int j = 1; j <= 3; j++) {
        const float inv = 2.0f / (float)j;
#pragma unroll
        for (int i = 0; i < 10 - j; i++) {
            const float ti = 0.5f * i - 2.5f;
            b[i] = (z - ti) * inv * b[i] + ((ti + 0.5f * (j + 1)) - z) * inv * b[i + 1];
        }
    }
#pragma unroll
    for (int g = 0; g < 7; g++) B[g] = b[g];
}

// ---------------- conversions ----------------
__global__ void pad_split(const float* __restrict__ src, int Nreal, int Kreal,
                          int Npad, int Kpad, ushort_t* __restrict__ hi,
                          ushort_t* __restrict__ lo) {
    const int total = Npad * Kpad;
    for (int idx = blockIdx.x * blockDim.x + threadIdx.x; idx < total;
         idx += gridDim.x * blockDim.x) {
        const int r = idx / Kpad, c = idx - r * Kpad;
        float v = (r < Nreal && c < Kreal) ? src[(size_t)r * Kreal + c] : 0.f;
        ushort_t h = f2bf(v);
        hi[idx] = h;
        lo[idx] = f2bf(v - bf2f(h));
    }
}

// W_exp[o][i*8+g] = g<7 ? spline_w[o][i][g] : base_w[o][i]; cols >= 1268*8 zero.
__global__ void conv_wk(const float* __restrict__ basew, const float* __restrict__ splinew,
                        ushort_t* __restrict__ hi, ushort_t* __restrict__ lo) {
    const int kp = blockIdx.x * blockDim.x + threadIdx.x;
    const int o = blockIdx.y;
    if (kp >= KPK) return;
    float v = 0.f;
    if (kp < 1268 * 8) {
        const int i = kp >> 3, g = kp & 7;
        v = (g < 7) ? splinew[((size_t)o * 1268 + i) * 7 + g] : basew[(size_t)o * 1268 + i];
    }
    ushort_t h = f2bf(v);
    hi[(size_t)o * KPK + kp] = h;
    lo[(size_t)o * KPK + kp] = f2bf(v - bf2f(h));
}

// ---------------- degree (proven round-1 path) ----------------
__global__ void deg_init(float* deg) {
    int i = blockIdx.x * blockDim.x + threadIdx.x;
    if (i < Nn) deg[i] = 1.f;   // self loop
}
__global__ void deg_edges(const int* __restrict__ ei, float* deg, int E) {
    for (int e = blockIdx.x * blockDim.x + threadIdx.x; e < E; e += gridDim.x * blockDim.x)
        atomAddF(&deg[ei[E + e]], 1.f);
}
__global__ void deg_finish(float* deg) {
    int i = blockIdx.x * blockDim.x + threadIdx.x;
    if (i < Nn) deg[i] = 1.f / sqrtf(deg[i]);
}
__global__ void agg_init(const float* __restrict__ cb, float* __restrict__ agg) {
    const int total = Nn * (Hdim / 4);
    const float4* c4 = (const float4*)cb;
    for (int i = blockIdx.x * blockDim.x + threadIdx.x; i < total; i += gridDim.x * blockDim.x)
        ((float4*)agg)[i] = c4[i & 63];
}
// one wave per edge; 64 lanes x float4 = 256 channels  (proven round-1)
__global__ void scatter_add(const float* __restrict__ z, const int* __restrict__ ei,
                            const float* __restrict__ dinv, float* __restrict__ agg, int E) {
    const int lane = threadIdx.x & 63;
    const int wid = (blockIdx.x * blockDim.x + threadIdx.x) >> 6;
    const int nw = (gridDim.x * blockDim.x) >> 6;
    const int total = E + Nn;
    for (int e = wid; e < total; e += nw) {
        int s, d;
        if (e < E) { s = ei[e]; d = ei[E + e]; }
        else { s = e - E; d = s; }
        const float w = dinv[s] * dinv[d];
        const float4 v = *(const float4*)(z + (size_t)s * Hdim + lane * 4);
        float* a = agg + (size_t)d * Hdim + lane * 4;
        atomAddF(a + 0, v.x * w);
        atomAddF(a + 1, v.y * w);
        atomAddF(a + 2, v.z * w);
        atomAddF(a + 3, v.w * w);
    }
}

// ---------------- BatchNorm ----------------
__global__ void bn_stats(const float* __restrict__ agg, float* __restrict__ stats) {
    const int col = threadIdx.x;
    const int r0 = blockIdx.x * 128;
    float s = 0.f, q = 0.f;
    for (int r = 0; r < 128; r++) {
        const float v = agg[(size_t)(r0 + r) * Hdim + col];
        s += v; q += v * v;
    }
    atomAddF(&stats[col], s);
    atomAddF(&stats[Hdim + col], q);
}
__global__ void bn_final(const float* __restrict__ stats, const float* __restrict__ g,
                         const float* __restrict__ b, float* __restrict__ sc,
                         float* __restrict__ sh) {
    const int c = threadIdx.x;
    const float mu = stats[c] * (1.f / Nn);
    const float var = stats[Hdim + c] * (1.f / Nn) - mu * mu;
    const float scale = rsqrtf(var + 1e-5f) * g[c];
    sc[c] = scale;
    sh[c] = b[c] - mu * scale;
}
// BN -> hfeat fp32 col block; also next-layer bf16 hi/lo activations (padded rows zeroed)
__global__ void bn_apply_conv(const float* __restrict__ agg, const float* __restrict__ sc,
                              const float* __restrict__ sh, float* __restrict__ hfeat,
                              int colBase, ushort_t* __restrict__ Anh,
                              ushort_t* __restrict__ Anl, int writeA) {
    const int total = Mpad * Hdim;
    for (int e = blockIdx.x * blockDim.x + threadIdx.x; e < total;
         e += gridDim.x * blockDim.x) {
        const int row = e >> 8, col = e & 255;
        if (row < Nn) {
            const float y = agg[e] * sc[col] + sh[col];
            hfeat[(size_t)row * HF + colBase + col] = y;
            if (writeA) {
                ushort_t h = f2bf(y);
                Anh[e] = h;
                Anl[e] = f2bf(y - bf2f(h));
            }
        } else if (writeA) {
            Anh[e] = 0;
            Anl[e] = 0;
        }
    }
}

// ---------------- bf16x3 MFMA GEMM core (reg-staged LDS, self-consistent XOR swizzle) ----
// C = A @ W^T.  A [Mpad x Kpad] hi/lo, W [Npad x Kpad] hi/lo.
// BM=128, BN=64, BK=64, 4 waves (2M x 2N), wave tile 64x32.
template <int EPI>
__global__ __launch_bounds__(256, 2) void gemm_fc(
    const ushort_t* __restrict__ Ahi, const ushort_t* __restrict__ Alo,
    const ushort_t* __restrict__ Whi, const ushort_t* __restrict__ Wlo,
    const float* __restrict__ bias, int Nreal, int Kpad,
    ushort_t* __restrict__ Thi, ushort_t* __restrict__ Tlo, int ldT,
    float* __restrict__ Z)
{
    __shared__ __align__(16) ushort_t Ah[128 * 64], Al[128 * 64];
    __shared__ __align__(16) ushort_t Wh[64 * 64], Wl[64 * 64];

    const int tid = threadIdx.x;
    const int w = tid >> 6, lane = tid & 63;
    const int brow = blockIdx.x * 128, bn0 = blockIdx.y * 64;
    const int r16 = lane & 15, kq = lane >> 4;
    const int wm = (w >> 1) * 64, wn = (w & 1) * 32;

    f32x4 acc[4][2];
#pragma unroll
    for (int mi = 0; mi < 4; mi++)
#pragma unroll
        for (int ni = 0; ni < 2; ni++) acc[mi][ni] = (f32x4){0.f, 0.f, 0.f, 0.f};

    for (int kt = 0; kt < Kpad; kt += 64) {
        bf16x8 rah[4], ral[4], rwh[2], rwl[2];
#pragma unroll
        for (int q = 0; q < 4; q++) {
            const int p = q * 256 + tid, row = p >> 3, sl = p & 7;
            const size_t go = (size_t)(brow + row) * Kpad + kt + sl * 8;
            rah[q] = *(const bf16x8*)(Ahi + go);
            ral[q] = *(const bf16x8*)(Alo + go);
        }
#pragma unroll
        for (int q = 0; q < 2; q++) {
            const int p = q * 256 + tid, row = p >> 3, sl = p & 7;
            const size_t go = (size_t)(bn0 + row) * Kpad + kt + sl * 8;
            rwh[q] = *(const bf16x8*)(Whi + go);
            rwl[q] = *(const bf16x8*)(Wlo + go);
        }
        __syncthreads();   // previous-iteration LDS reads complete
#pragma unroll
        for (int q = 0; q < 4; q++) {
            const int p = q * 256 + tid, row = p >> 3, sl = p & 7;
            const int ph = sl ^ (row & 7);
            *(bf16x8*)&Ah[row * 64 + ph * 8] = rah[q];
            *(bf16x8*)&Al[row * 64 + ph * 8] = ral[q];
        }
#pragma unroll
        for (int q = 0; q < 2; q++) {
            const int p = q * 256 + tid, row = p >> 3, sl = p & 7;
            const int ph = sl ^ (row & 7);
            *(bf16x8*)&Wh[row * 64 + ph * 8] = rwh[q];
            *(bf16x8*)&Wl[row * 64 + ph * 8] = rwl[q];
        }
        __syncthreads();

#pragma unroll
        for (int h = 0; h < 2; h++) {
            bf16x8 a_h[4], a_l[4], w_h[2], w_l[2];
#pragma unroll
            for (int mi = 0; mi < 4; mi++) {
                const int row = wm + mi * 16 + r16;
                const int ss = (h * 4 + kq) ^ (row & 7);
                a_h[mi] = *(const bf16x8*)&Ah[row * 64 + ss * 8];
                a_l[mi] = *(const bf16x8*)&Al[row * 64 + ss * 8];
            }
#pragma unroll
            for (int ni = 0; ni < 2; ni++) {
                const int row = wn + ni * 16 + r16;
                const int ss = (h * 4 + kq) ^ (row & 7);
                w_h[ni] = *(const bf16x8*)&Wh[row * 64 + ss * 8];
                w_l[ni] = *(const bf16x8*)&Wl[row * 64 + ss * 8];
            }
#pragma unroll
            for (int mi = 0; mi < 4; mi++)
#pragma unroll
                for (int ni = 0; ni < 2; ni++) {
                    acc[mi][ni] = __builtin_amdgcn_mfma_f32_16x16x32_bf16(a_h[mi], w_h[ni], acc[mi][ni], 0, 0, 0);
                    acc[mi][ni] = __builtin_amdgcn_mfma_f32_16x16x32_bf16(a_h[mi], w_l[ni], acc[mi][ni], 0, 0, 0);
                    acc[mi][ni] = __builtin_amdgcn_mfma_f32_16x16x32_bf16(a_l[mi], w_h[ni], acc[mi][ni], 0, 0, 0);
                }
        }
        __syncthreads();
    }

#pragma unroll
    for (int mi = 0; mi < 4; mi++)
#pragma unroll
        for (int ni = 0; ni < 2; ni++)
#pragma unroll
            for (int e = 0; e < 4; e++) {
                const int row = brow + wm + mi * 16 + kq * 4 + e;
                const int col = bn0 + wn + ni * 16 + r16;
                float v = acc[mi][ni][e];
                const float bv = (col < Nreal) ? bias[col] : 0.f;
                if (EPI == 0) {
                    v = geluf(v + bv);
                    const ushort_t hb = f2bf(v);
                    Thi[(size_t)row * ldT + col] = hb;
                    Tlo[(size_t)row * ldT + col] = f2bf(v - bf2f(hb));
                } else {
                    Z[(size_t)row * Hdim + col] = v + bv;
                }
            }
}

// ---------------- fused KAN head as bf16x3 MFMA GEMM ----------------
__global__ __launch_bounds__(256, 2) void kan_gemm(
    const float* __restrict__ x, const float* __restrict__ hfeat,
    const ushort_t* __restrict__ WKhi, const ushort_t* __restrict__ WKlo,
    float* __restrict__ out)
{
    __shared__ __align__(16) ushort_t Ah[128 * 64], Al[128 * 64];
    __shared__ __align__(16) ushort_t Wh[64 * 64], Wl[64 * 64];

    const int tid = threadIdx.x;
    const int w = tid >> 6, lane = tid & 63;
    const int brow = blockIdx.x * 128;
    const int c0 = blockIdx.y * 32;
    const int nch = (159 - c0 < 32) ? (159 - c0) : 32;
    const int r16 = lane & 15, kq = lane >> 4;
    const int wm = (w >> 1) * 64, wn = (w & 1) * 32;

    f32x4 acc[4][2];
#pragma unroll
    for (int mi = 0; mi < 4; mi++)
#pragma unroll
        for (int ni = 0; ni < 2; ni++) acc[mi][ni] = (f32x4){0.f, 0.f, 0.f, 0.f};

    for (int ch = 0; ch < nch; ch++) {
        const int ck = (c0 + ch) * 64;

        bf16x8 rwh[2], rwl[2];
#pragma unroll
        for (int q = 0; q < 2; q++) {
            const int p = q * 256 + tid, row = p >> 3, sl = p & 7;
            const size_t go = (size_t)row * KPK + ck + sl * 8;
            rwh[q] = *(const bf16x8*)(WKhi + go);
            rwl[q] = *(const bf16x8*)(WKlo + go);
        }
        float zq[4];
#pragma unroll
        for (int q = 0; q < 4; q++) {
            const int p = q * 256 + tid, row = p >> 3, sl = p & 7;
            const int i = (ck >> 3) + sl;
            const int grow = brow + row;
            float z = 0.f;
            if (grow < Nn && i < 1268)
                z = (i < Fdim) ? x[(size_t)grow * Fdim + i]
                               : hfeat[(size_t)grow * HF + (i - Fdim)];
            zq[q] = z;
        }
        __syncthreads();

#pragma unroll
        for (int q = 0; q < 2; q++) {
            const int p = q * 256 + tid, row = p >> 3, sl = p & 7;
            const int ph = sl ^ (row & 7);
            *(bf16x8*)&Wh[row * 64 + ph * 8] = rwh[q];
            *(bf16x8*)&Wl[row * 64 + ph * 8] = rwl[q];
        }
#pragma unroll
        for (int q = 0; q < 4; q++) {
            const int p = q * 256 + tid, row = p >> 3, sl = p & 7;
            const int ph = sl ^ (row & 7);
            float v[8];
            bspl7(zq[q], v);
            v[7] = siluf(zq[q]);
            bf16x8 hv, lv;
#pragma unroll
            for (int j = 0; j < 8; j++) {
                const ushort_t hb = f2bf(v[j]);
                hv[j] = (short)hb;
                lv[j] = (short)f2bf(v[j] - bf2f(hb));
            }
            *(bf16x8*)&Ah[row * 64 + ph * 8] = hv;
            *(bf16x8*)&Al[row * 64 + ph * 8] = lv;
        }
        __syncthreads();

#pragma unroll
        for (int h = 0; h < 2; h++) {
            bf16x8 a_h[4], a_l[4], w_h[2], w_l[2];
#pragma unroll
            for (int mi = 0; mi < 4; mi++) {
                const int row = wm + mi * 16 + r16;
                const int ss = (h * 4 + kq) ^ (row & 7);
                a_h[mi] = *(const bf16x8*)&Ah[row * 64 + ss * 8];
                a_l[mi] = *(const bf16x8*)&Al[row * 64 + ss * 8];
            }
#pragma unroll
            for (int ni = 0; ni < 2; ni++) {
                const int row = wn + ni * 16 + r16;
                const int ss = (h * 4 + kq) ^ (row & 7);
                w_h[ni] = *(const bf16x8*)&Wh[row * 64 + ss * 8];
                w_l[ni] = *(const bf16x8*)&Wl[row * 64 + ss * 8];
            }
#pragma unroll
            for (int mi = 0; mi < 4; mi++)
#pragma unroll
                for (int ni = 0; ni < 2; ni++) {
                    acc[mi][ni] = __builtin_amdgcn_mfma_f32_16x16x32_bf16(a_h[mi], w_h[ni], acc[mi][ni], 0, 0, 0);
                    acc[mi][ni] = __builtin_amdgcn_mfma_f32_16x16x32_bf16(a_h[mi], w_l[ni], acc[mi][ni], 0, 0, 0);
                    acc[mi][ni] = __builtin_amdgcn_mfma_f32_16x16x32_bf16(a_l[mi], w_h[ni], acc[mi][ni], 0, 0, 0);
                }
        }
        __syncthreads();
    }

#pragma unroll
    for (int mi = 0; mi < 4; mi++)
#pragma unroll
        for (int ni = 0; ni < 2; ni++)
#pragma unroll
            for (int e = 0; e < 4; e++) {
                const int row = brow + wm + mi * 16 + kq * 4 + e;
                if (row < Nn) {
                    const int col = wn + ni * 16 + r16;
                    atomAddF(&out[(size_t)row * Cdim + col], acc[mi][ni][e]);
                }
            }
}

// ---------------- launch ----------------
extern "C" void kernel_launch(void* const* d_in, const int* in_sizes, int n_in,
                              void* d_out, int out_size, void* d_ws, size_t ws_size,
                              hipStream_t stream)
{
    const float* x = (const float*)d_in[0];
    const float *fc1w[3], *fc1b[3], *fc2w[3], *fc2b[3], *cb[3], *bg[3], *bb[3];
    for (int l = 0; l < 3; l++) {
        const int base = 1 + l * 7;
        fc1w[l] = (const float*)d_in[base + 0];
        fc1b[l] = (const float*)d_in[base + 1];
        fc2w[l] = (const float*)d_in[base + 2];
        fc2b[l] = (const float*)d_in[base + 3];
        cb[l]   = (const float*)d_in[base + 4];
        bg[l]   = (const float*)d_in[base + 5];
        bb[l]   = (const float*)d_in[base + 6];
    }
    const float* base_w   = (const float*)d_in[22];
    const float* spline_w = (const float*)d_in[23];
    const int*   ei       = (const int*)d_in[24];
    const int    E        = in_sizes[24] / 2;
    float*       out      = (float*)d_out;

    // ---- workspace layout (ran on HW in rounds 2/3; fits) ----
    size_t off = 0;
    auto alloc = [&](size_t bytes) {
        void* p = (char*)d_ws + off;
        off = (off + bytes + 255) & ~(size_t)255;
        return p;
    };
    float*    hfeat = (float*)alloc((size_t)Nn * HF * 4);          // 49.2 MB
    char*     RA    = (char*)alloc(33030144);                      // 16128x512 bf16 x2
    char*     RB    = (char*)alloc(33030144);
    ushort_t* w1hi[3]; ushort_t* w1lo[3]; ushort_t* w2hi[3]; ushort_t* w2lo[3];
    for (int l = 0; l < 3; l++) {
        w1hi[l] = (ushort_t*)alloc(524288); w1lo[l] = (ushort_t*)alloc(524288);
        w2hi[l] = (ushort_t*)alloc(524288); w2lo[l] = (ushort_t*)alloc(524288);
    }
    ushort_t* wkhi = (ushort_t*)alloc((size_t)Cdim * KPK * 2);
    ushort_t* wklo = (ushort_t*)alloc((size_t)Cdim * KPK * 2);
    float* dinv   = (float*)alloc(Nn * 4);
    float* stats  = (float*)alloc(2048 * 4);
    float* bnsc = stats + 512;
    float* bnsh = stats + 768;
    if (off > ws_size) return;

    // aliases:
    ushort_t* A0hi = (ushort_t*)RA;                    // x split [16128x512]
    ushort_t* A0lo = (ushort_t*)(RA + 16515072);
    float*    zbuf = (float*)RA;                       // fc2 out, after A0 dead
    ushort_t* Anhi = (ushort_t*)(RA + 16515072);       // next-layer activations [16128x256]
    ushort_t* Anlo = (ushort_t*)(RA + 24772608);
    ushort_t* Thi  = (ushort_t*)RB;                    // fc1 out [16128 x <=512]
    ushort_t* Tlo  = (ushort_t*)(RB + 16515072);
    float*    agg  = (float*)RB;                       // aggregation, after T dead

    const dim3 blk(256);

    hipMemsetAsync(out, 0, (size_t)Nn * Cdim * 4, stream);

    // conversions
    pad_split<<<4096, blk, 0, stream>>>(x, Nn, Fdim, Mpad, 512, A0hi, A0lo);
    pad_split<<<1024, blk, 0, stream>>>(fc1w[0], 500, 500, 512, 512, w1hi[0], w1lo[0]);
    pad_split<<<512,  blk, 0, stream>>>(fc1w[1], 256, 256, 256, 256, w1hi[1], w1lo[1]);
    pad_split<<<512,  blk, 0, stream>>>(fc1w[2], 256, 256, 256, 256, w1hi[2], w1lo[2]);
    pad_split<<<512,  blk, 0, stream>>>(fc2w[0], 256, 500, 256, 512, w2hi[0], w2lo[0]);
    pad_split<<<512,  blk, 0, stream>>>(fc2w[1], 256, 256, 256, 256, w2hi[1], w2lo[1]);
    pad_split<<<512,  blk, 0, stream>>>(fc2w[2], 256, 256, 256, 256, w2hi[2], w2lo[2]);
    conv_wk<<<dim3((KPK + 255) / 256, Cdim), blk, 0, stream>>>(base_w, spline_w, wkhi, wklo);

    // degrees (proven round-1 path)
    deg_init<<<(Nn + 255) / 256, blk, 0, stream>>>(dinv);
    deg_edges<<<1024, blk, 0, stream>>>(ei, dinv, E);
    deg_finish<<<(Nn + 255) / 256, blk, 0, stream>>>(dinv);

    for (int l = 0; l < 3; l++) {
        const int Kp    = (l == 0) ? 512 : 256;   // fc1 K (padded)
        const int Npad1 = (l == 0) ? 512 : 256;   // fc1 Nout (padded) == fc2 K
        const int Nr1   = (l == 0) ? 500 : 256;
        const ushort_t* Ah_p = (l == 0) ? A0hi : Anhi;
        const ushort_t* Al_p = (l == 0) ? A0lo : Anlo;

        gemm_fc<0><<<dim3(126, Npad1 / 64), blk, 0, stream>>>(
            Ah_p, Al_p, w1hi[l], w1lo[l], fc1b[l], Nr1, Kp, Thi, Tlo, Npad1, nullptr);
        gemm_fc<1><<<dim3(126, 4), blk, 0, stream>>>(
            Thi, Tlo, w2hi[l], w2lo[l], fc2b[l], 256, Npad1, nullptr, nullptr, 0, zbuf);

        agg_init<<<2048, blk, 0, stream>>>(cb[l], agg);
        scatter_add<<<2048, blk, 0, stream>>>(zbuf, ei, dinv, agg, E);

        hipMemsetAsync(stats, 0, 512 * 4, stream);
        bn_stats<<<125, blk, 0, stream>>>(agg, stats);
        bn_final<<<1, blk, 0, stream>>>(stats, bg[l], bb[l], bnsc, bnsh);
        bn_apply_conv<<<4096, blk, 0, stream>>>(agg, bnsc, bnsh, hfeat, l * Hdim,
                                                Anhi, Anlo, (l < 2) ? 1 : 0);
    }

    kan_gemm<<<dim3(126, 5), blk, 0, stream>>>(x, hfeat, wkhi, wklo, out);
}

// Round 10
// 805.506 us; speedup vs baseline: 8.1144x; 5.9568x over previous
//
#include <hip/hip_runtime.h>
#include <cstddef>
#include <cstdint>

typedef unsigned short ushort_t;
typedef __attribute__((ext_vector_type(8))) short bf16x8;
typedef __attribute__((ext_vector_type(4))) float f32x4;

static constexpr int Nn   = 16000;
static constexpr int Mpad = 16128;   // 126*128
static constexpr int Fdim = 500;
static constexpr int Hdim = 256;
static constexpr int Cdim = 64;
static constexpr int HF   = 768;     // hfeat cols (3*256)
static constexpr int KPK  = 10176;   // kan expanded K padded (159*64)

// ---------------- scalar helpers ----------------
__device__ __forceinline__ float geluf(float v) {
    return 0.5f * v * (1.f + erff(v * 0.70710678118654752440f));
}
__device__ __forceinline__ float siluf(float v) {
    return v / (1.f + expf(-v));
}
__device__ __forceinline__ void atomAddF(float* p, float v) { unsafeAtomicAdd(p, v); }

__device__ __forceinline__ ushort_t f2bf(float x) {
    uint32_t u = __float_as_uint(x);
    uint32_t r = (u + 0x7fffu + ((u >> 16) & 1u)) >> 16;
    return (ushort_t)r;
}
__device__ __forceinline__ float bf2f(ushort_t b) {
    return __uint_as_float(((uint32_t)b) << 16);
}

// cubic B-splines, uniform knots t_i = 0.5 i - 2.5 (i=0..10) -> 7 bases.
// PROVEN index-free form (rounds 1/9). Do NOT rewrite with a knot-diff array:
// the d[10] variant OOB-read d[i+j+1]==d[10] (11 knots) — rounds 2/3/8 bug.
__device__ __forceinline__ void bspl7(float z, float* B) {
    float b[10];
#pragma unroll
    for (int i = 0; i < 10; i++) {
        const float t0 = 0.5f * i - 2.5f;
        b[i] = (z >= t0 && z < t0 + 0.5f) ? 1.f : 0.f;
    }
#pragma unroll
    for (int j = 1; j <= 3; j++) {
        const float inv = 2.0f / (float)j;
#pragma unroll
        for (int i = 0; i < 10 - j; i++) {
            const float ti = 0.5f * i - 2.5f;
            b[i] = (z - ti) * inv * b[i] + ((ti + 0.5f * (j + 1)) - z) * inv * b[i + 1];
        }
    }
#pragma unroll
    for (int g = 0; g < 7; g++) B[g] = b[g];
}

// ---------------- conversions ----------------
__global__ void pad_split(const float* __restrict__ src, int Nreal, int Kreal,
                          int Npad, int Kpad, ushort_t* __restrict__ hi,
                          ushort_t* __restrict__ lo) {
    const int total = Npad * Kpad;
    for (int idx = blockIdx.x * blockDim.x + threadIdx.x; idx < total;
         idx += gridDim.x * blockDim.x) {
        const int r = idx / Kpad, c = idx - r * Kpad;
        float v = (r < Nreal && c < Kreal) ? src[(size_t)r * Kreal + c] : 0.f;
        ushort_t h = f2bf(v);
        hi[idx] = h;
        lo[idx] = f2bf(v - bf2f(h));
    }
}

// W_exp[o][i*8+g] = g<7 ? spline_w[o][i][g] : base_w[o][i]; cols >= 1268*8 zero.
__global__ void conv_wk(const float* __restrict__ basew, const float* __restrict__ splinew,
                        ushort_t* __restrict__ hi, ushort_t* __restrict__ lo) {
    const int kp = blockIdx.x * blockDim.x + threadIdx.x;
    const int o = blockIdx.y;
    if (kp >= KPK) return;
    float v = 0.f;
    if (kp < 1268 * 8) {
        const int i = kp >> 3, g = kp & 7;
        v = (g < 7) ? splinew[((size_t)o * 1268 + i) * 7 + g] : basew[(size_t)o * 1268 + i];
    }
    ushort_t h = f2bf(v);
    hi[(size_t)o * KPK + kp] = h;
    lo[(size_t)o * KPK + kp] = f2bf(v - bf2f(h));
}

// ---------------- CSR build (replaces atomic scatter: 87% of round-9 time) ----------------
__global__ void deg_hist(const int* __restrict__ ei, int* __restrict__ deg, int E) {
    for (int e = blockIdx.x * blockDim.x + threadIdx.x; e < E; e += gridDim.x * blockDim.x)
        atomicAdd(&deg[ei[E + e]], 1);
}
// single block 1024 threads: exclusive scan of (deg+1); also start/cursor/dinv
__global__ void scan16k(const int* __restrict__ deg, int* __restrict__ start,
                        int* __restrict__ cursor, float* __restrict__ dinv) {
    __shared__ int part[1024];
    const int t = threadIdx.x;
    const int base = t * 16;
    int loc[16];
    int s = 0;
#pragma unroll
    for (int j = 0; j < 16; j++) {
        const int idx = base + j;
        const int d = (idx < Nn) ? deg[idx] + 1 : 0;   // +1 self loop
        loc[j] = d;
        s += d;
    }
    part[t] = s;
    __syncthreads();
    for (int off = 1; off < 1024; off <<= 1) {
        int v = part[t];
        int u = (t >= off) ? part[t - off] : 0;
        __syncthreads();
        part[t] = v + u;
        __syncthreads();
    }
    int run = part[t] - s;   // exclusive prefix of this thread's chunk
#pragma unroll
    for (int j = 0; j < 16; j++) {
        const int idx = base + j;
        if (idx < Nn) {
            start[idx] = run;
            cursor[idx] = run;
            dinv[idx] = rsqrtf((float)loc[j]);
            run += loc[j];
        }
    }
    if (t == 1023) start[Nn] = part[1023];
}
__global__ void csr_fill(const int* __restrict__ ei, int* __restrict__ cursor,
                         int* __restrict__ csr, int E) {
    const int total = E + Nn;
    for (int i = blockIdx.x * blockDim.x + threadIdx.x; i < total;
         i += gridDim.x * blockDim.x) {
        int s, d;
        if (i < E) { s = ei[i]; d = ei[E + i]; }
        else { s = d = i - E; }
        const int pos = atomicAdd(&cursor[d], 1);
        csr[pos] = s;
    }
}

// ---------------- gather aggregation (one wave per node, zero hot-path atomics) --------
__global__ void gather_agg(const float* __restrict__ z, const int* __restrict__ csr,
                           const int* __restrict__ start, const float* __restrict__ dinv,
                           const float* __restrict__ cb, float* __restrict__ agg) {
    const int wid = (blockIdx.x * blockDim.x + threadIdx.x) >> 6;
    const int lane = threadIdx.x & 63;
    if (wid >= Nn) return;
    float4 acc = ((const float4*)cb)[lane];
    const float dn = dinv[wid];
    const int b = start[wid], e = start[wid + 1];
    for (int j = b; j < e; j++) {
        const int s = csr[j];
        const float w = dn * dinv[s];
        const float4 v = ((const float4*)(z + (size_t)s * Hdim))[lane];
        acc.x += v.x * w; acc.y += v.y * w; acc.z += v.z * w; acc.w += v.w * w;
    }
    ((float4*)(agg + (size_t)wid * Hdim))[lane] = acc;
}

// ---------------- BatchNorm ----------------
__global__ void bn_stats(const float* __restrict__ agg, float* __restrict__ stats) {
    const int col = threadIdx.x;
    const int r0 = blockIdx.x * 128;
    float s = 0.f, q = 0.f;
    for (int r = 0; r < 128; r++) {
        const float v = agg[(size_t)(r0 + r) * Hdim + col];
        s += v; q += v * v;
    }
    atomAddF(&stats[col], s);
    atomAddF(&stats[Hdim + col], q);
}
__global__ void bn_final(const float* __restrict__ stats, const float* __restrict__ g,
                         const float* __restrict__ b, float* __restrict__ sc,
                         float* __restrict__ sh) {
    const int c = threadIdx.x;
    const float mu = stats[c] * (1.f / Nn);
    const float var = stats[Hdim + c] * (1.f / Nn) - mu * mu;
    const float scale = rsqrtf(var + 1e-5f) * g[c];
    sc[c] = scale;
    sh[c] = b[c] - mu * scale;
}
// BN -> hfeat fp32 col block; also next-layer bf16 hi/lo activations (padded rows zeroed)
__global__ void bn_apply_conv(const float* __restrict__ agg, const float* __restrict__ sc,
                              const float* __restrict__ sh, float* __restrict__ hfeat,
                              int colBase, ushort_t* __restrict__ Anh,
                              ushort_t* __restrict__ Anl, int writeA) {
    const int total = Mpad * Hdim;
    for (int e = blockIdx.x * blockDim.x + threadIdx.x; e < total;
         e += gridDim.x * blockDim.x) {
        const int row = e >> 8, col = e & 255;
        if (row < Nn) {
            const float y = agg[e] * sc[col] + sh[col];
            hfeat[(size_t)row * HF + colBase + col] = y;
            if (writeA) {
                ushort_t h = f2bf(y);
                Anh[e] = h;
                Anl[e] = f2bf(y - bf2f(h));
            }
        } else if (writeA) {
            Anh[e] = 0;
            Anl[e] = 0;
        }
    }
}

// ---------------- bf16x3 MFMA GEMM core (reg-staged LDS, self-consistent XOR swizzle) ----
template <int EPI>
__global__ __launch_bounds__(256, 2) void gemm_fc(
    const ushort_t* __restrict__ Ahi, const ushort_t* __restrict__ Alo,
    const ushort_t* __restrict__ Whi, const ushort_t* __restrict__ Wlo,
    const float* __restrict__ bias, int Nreal, int Kpad,
    ushort_t* __restrict__ Thi, ushort_t* __restrict__ Tlo, int ldT,
    float* __restrict__ Z)
{
    __shared__ __align__(16) ushort_t Ah[128 * 64], Al[128 * 64];
    __shared__ __align__(16) ushort_t Wh[64 * 64], Wl[64 * 64];

    const int tid = threadIdx.x;
    const int w = tid >> 6, lane = tid & 63;
    const int brow = blockIdx.x * 128, bn0 = blockIdx.y * 64;
    const int r16 = lane & 15, kq = lane >> 4;
    const int wm = (w >> 1) * 64, wn = (w & 1) * 32;

    f32x4 acc[4][2];
#pragma unroll
    for (int mi = 0; mi < 4; mi++)
#pragma unroll
        for (int ni = 0; ni < 2; ni++) acc[mi][ni] = (f32x4){0.f, 0.f, 0.f, 0.f};

    for (int kt = 0; kt < Kpad; kt += 64) {
        bf16x8 rah[4], ral[4], rwh[2], rwl[2];
#pragma unroll
        for (int q = 0; q < 4; q++) {
            const int p = q * 256 + tid, row = p >> 3, sl = p & 7;
            const size_t go = (size_t)(brow + row) * Kpad + kt + sl * 8;
            rah[q] = *(const bf16x8*)(Ahi + go);
            ral[q] = *(const bf16x8*)(Alo + go);
        }
#pragma unroll
        for (int q = 0; q < 2; q++) {
            const int p = q * 256 + tid, row = p >> 3, sl = p & 7;
            const size_t go = (size_t)(bn0 + row) * Kpad + kt + sl * 8;
            rwh[q] = *(const bf16x8*)(Whi + go);
            rwl[q] = *(const bf16x8*)(Wlo + go);
        }
        __syncthreads();   // previous-iteration LDS reads complete
#pragma unroll
        for (int q = 0; q < 4; q++) {
            const int p = q * 256 + tid, row = p >> 3, sl = p & 7;
            const int ph = sl ^ (row & 7);
            *(bf16x8*)&Ah[row * 64 + ph * 8] = rah[q];
            *(bf16x8*)&Al[row * 64 + ph * 8] = ral[q];
        }
#pragma unroll
        for (int q = 0; q < 2; q++) {
            const int p = q * 256 + tid, row = p >> 3, sl = p & 7;
            const int ph = sl ^ (row & 7);
            *(bf16x8*)&Wh[row * 64 + ph * 8] = rwh[q];
            *(bf16x8*)&Wl[row * 64 + ph * 8] = rwl[q];
        }
        __syncthreads();

#pragma unroll
        for (int h = 0; h < 2; h++) {
            bf16x8 a_h[4], a_l[4], w_h[2], w_l[2];
#pragma unroll
            for (int mi = 0; mi < 4; mi++) {
                const int row = wm + mi * 16 + r16;
                const int ss = (h * 4 + kq) ^ (row & 7);
                a_h[mi] = *(const bf16x8*)&Ah[row * 64 + ss * 8];
                a_l[mi] = *(const bf16x8*)&Al[row * 64 + ss * 8];
            }
#pragma unroll
            for (int ni = 0; ni < 2; ni++) {
                const int row = wn + ni * 16 + r16;
                const int ss = (h * 4 + kq) ^ (row & 7);
                w_h[ni] = *(const bf16x8*)&Wh[row * 64 + ss * 8];
                w_l[ni] = *(const bf16x8*)&Wl[row * 64 + ss * 8];
            }
#pragma unroll
            for (int mi = 0; mi < 4; mi++)
#pragma unroll
                for (int ni = 0; ni < 2; ni++) {
                    acc[mi][ni] = __builtin_amdgcn_mfma_f32_16x16x32_bf16(a_h[mi], w_h[ni], acc[mi][ni], 0, 0, 0);
                    acc[mi][ni] = __builtin_amdgcn_mfma_f32_16x16x32_bf16(a_h[mi], w_l[ni], acc[mi][ni], 0, 0, 0);
                    acc[mi][ni] = __builtin_amdgcn_mfma_f32_16x16x32_bf16(a_l[mi], w_h[ni], acc[mi][ni], 0, 0, 0);
                }
        }
        __syncthreads();
    }

#pragma unroll
    for (int mi = 0; mi < 4; mi++)
#pragma unroll
        for (int ni = 0; ni < 2; ni++)
#pragma unroll
            for (int e = 0; e < 4; e++) {
                const int row = brow + wm + mi * 16 + kq * 4 + e;
                const int col = bn0 + wn + ni * 16 + r16;
                float v = acc[mi][ni][e];
                const float bv = (col < Nreal) ? bias[col] : 0.f;
                if (EPI == 0) {
                    v = geluf(v + bv);
                    const ushort_t hb = f2bf(v);
                    Thi[(size_t)row * ldT + col] = hb;
                    Tlo[(size_t)row * ldT + col] = f2bf(v - bf2f(hb));
                } else {
                    Z[(size_t)row * Hdim + col] = v + bv;
                }
            }
}

// ---------------- fused KAN head as bf16x3 MFMA GEMM ----------------
__global__ __launch_bounds__(256, 2) void kan_gemm(
    const float* __restrict__ x, const float* __restrict__ hfeat,
    const ushort_t* __restrict__ WKhi, const ushort_t* __restrict__ WKlo,
    float* __restrict__ out)
{
    __shared__ __align__(16) ushort_t Ah[128 * 64], Al[128 * 64];
    __shared__ __align__(16) ushort_t Wh[64 * 64], Wl[64 * 64];

    const int tid = threadIdx.x;
    const int w = tid >> 6, lane = tid & 63;
    const int brow = blockIdx.x * 128;
    const int c0 = blockIdx.y * 32;
    const int nch = (159 - c0 < 32) ? (159 - c0) : 32;
    const int r16 = lane & 15, kq = lane >> 4;
    const int wm = (w >> 1) * 64, wn = (w & 1) * 32;

    f32x4 acc[4][2];
#pragma unroll
    for (int mi = 0; mi < 4; mi++)
#pragma unroll
        for (int ni = 0; ni < 2; ni++) acc[mi][ni] = (f32x4){0.f, 0.f, 0.f, 0.f};

    for (int ch = 0; ch < nch; ch++) {
        const int ck = (c0 + ch) * 64;

        bf16x8 rwh[2], rwl[2];
#pragma unroll
        for (int q = 0; q < 2; q++) {
            const int p = q * 256 + tid, row = p >> 3, sl = p & 7;
            const size_t go = (size_t)row * KPK + ck + sl * 8;
            rwh[q] = *(const bf16x8*)(WKhi + go);
            rwl[q] = *(const bf16x8*)(WKlo + go);
        }
        float zq[4];
#pragma unroll
        for (int q = 0; q < 4; q++) {
            const int p = q * 256 + tid, row = p >> 3, sl = p & 7;
            const int i = (ck >> 3) + sl;
            const int grow = brow + row;
            float z = 0.f;
            if (grow < Nn && i < 1268)
                z = (i < Fdim) ? x[(size_t)grow * Fdim + i]
                               : hfeat[(size_t)grow * HF + (i - Fdim)];
            zq[q] = z;
        }
        __syncthreads();

#pragma unroll
        for (int q = 0; q < 2; q++) {
            const int p = q * 256 + tid, row = p >> 3, sl = p & 7;
            const int ph = sl ^ (row & 7);
            *(bf16x8*)&Wh[row * 64 + ph * 8] = rwh[q];
            *(bf16x8*)&Wl[row * 64 + ph * 8] = rwl[q];
        }
#pragma unroll
        for (int q = 0; q < 4; q++) {
            const int p = q * 256 + tid, row = p >> 3, sl = p & 7;
            const int ph = sl ^ (row & 7);
            float v[8];
            bspl7(zq[q], v);
            v[7] = siluf(zq[q]);
            bf16x8 hv, lv;
#pragma unroll
            for (int j = 0; j < 8; j++) {
                const ushort_t hb = f2bf(v[j]);
                hv[j] = (short)hb;
                lv[j] = (short)f2bf(v[j] - bf2f(hb));
            }
            *(bf16x8*)&Ah[row * 64 + ph * 8] = hv;
            *(bf16x8*)&Al[row * 64 + ph * 8] = lv;
        }
        __syncthreads();

#pragma unroll
        for (int h = 0; h < 2; h++) {
            bf16x8 a_h[4], a_l[4], w_h[2], w_l[2];
#pragma unroll
            for (int mi = 0; mi < 4; mi++) {
                const int row = wm + mi * 16 + r16;
                const int ss = (h * 4 + kq) ^ (row & 7);
                a_h[mi] = *(const bf16x8*)&Ah[row * 64 + ss * 8];
                a_l[mi] = *(const bf16x8*)&Al[row * 64 + ss * 8];
            }
#pragma unroll
            for (int ni = 0; ni < 2; ni++) {
                const int row = wn + ni * 16 + r16;
                const int ss = (h * 4 + kq) ^ (row & 7);
                w_h[ni] = *(const bf16x8*)&Wh[row * 64 + ss * 8];
                w_l[ni] = *(const bf16x8*)&Wl[row * 64 + ss * 8];
            }
#pragma unroll
            for (int mi = 0; mi < 4; mi++)
#pragma unroll
                for (int ni = 0; ni < 2; ni++) {
                    acc[mi][ni] = __builtin_amdgcn_mfma_f32_16x16x32_bf16(a_h[mi], w_h[ni], acc[mi][ni], 0, 0, 0);
                    acc[mi][ni] = __builtin_amdgcn_mfma_f32_16x16x32_bf16(a_h[mi], w_l[ni], acc[mi][ni], 0, 0, 0);
                    acc[mi][ni] = __builtin_amdgcn_mfma_f32_16x16x32_bf16(a_l[mi], w_h[ni], acc[mi][ni], 0, 0, 0);
                }
        }
        __syncthreads();
    }

#pragma unroll
    for (int mi = 0; mi < 4; mi++)
#pragma unroll
        for (int ni = 0; ni < 2; ni++)
#pragma unroll
            for (int e = 0; e < 4; e++) {
                const int row = brow + wm + mi * 16 + kq * 4 + e;
                if (row < Nn) {
                    const int col = wn + ni * 16 + r16;
                    atomAddF(&out[(size_t)row * Cdim + col], acc[mi][ni][e]);
                }
            }
}

// ---------------- launch ----------------
extern "C" void kernel_launch(void* const* d_in, const int* in_sizes, int n_in,
                              void* d_out, int out_size, void* d_ws, size_t ws_size,
                              hipStream_t stream)
{
    const float* x = (const float*)d_in[0];
    const float *fc1w[3], *fc1b[3], *fc2w[3], *fc2b[3], *cb[3], *bg[3], *bb[3];
    for (int l = 0; l < 3; l++) {
        const int base = 1 + l * 7;
        fc1w[l] = (const float*)d_in[base + 0];
        fc1b[l] = (const float*)d_in[base + 1];
        fc2w[l] = (const float*)d_in[base + 2];
        fc2b[l] = (const float*)d_in[base + 3];
        cb[l]   = (const float*)d_in[base + 4];
        bg[l]   = (const float*)d_in[base + 5];
        bb[l]   = (const float*)d_in[base + 6];
    }
    const float* base_w   = (const float*)d_in[22];
    const float* spline_w = (const float*)d_in[23];
    const int*   ei       = (const int*)d_in[24];
    const int    E        = in_sizes[24] / 2;
    float*       out      = (float*)d_out;

    // ---- workspace layout (round-9 proven layout + small CSR arrays) ----
    size_t off = 0;
    auto alloc = [&](size_t bytes) {
        void* p = (char*)d_ws + off;
        off = (off + bytes + 255) & ~(size_t)255;
        return p;
    };
    float*    hfeat = (float*)alloc((size_t)Nn * HF * 4);          // 49.2 MB
    char*     RA    = (char*)alloc(33030144);                      // 16128x512 bf16 x2
    char*     RB    = (char*)alloc(33030144);
    ushort_t* w1hi[3]; ushort_t* w1lo[3]; ushort_t* w2hi[3]; ushort_t* w2lo[3];
    for (int l = 0; l < 3; l++) {
        w1hi[l] = (ushort_t*)alloc(524288); w1lo[l] = (ushort_t*)alloc(524288);
        w2hi[l] = (ushort_t*)alloc(524288); w2lo[l] = (ushort_t*)alloc(524288);
    }
    ushort_t* wkhi = (ushort_t*)alloc((size_t)Cdim * KPK * 2);
    ushort_t* wklo = (ushort_t*)alloc((size_t)Cdim * KPK * 2);
    int*   csr    = (int*)alloc((size_t)(E + Nn) * 4);
    int*   startA = (int*)alloc((Nn + 4) * 4);
    int*   cursor = (int*)alloc(Nn * 4);
    int*   deg    = (int*)alloc(Nn * 4);
    float* dinv   = (float*)alloc(Nn * 4);
    float* stats  = (float*)alloc(2048 * 4);
    float* bnsc = stats + 512;
    float* bnsh = stats + 768;
    if (off > ws_size) return;

    // aliases:
    ushort_t* A0hi = (ushort_t*)RA;                    // x split [16128x512]
    ushort_t* A0lo = (ushort_t*)(RA + 16515072);
    float*    zbuf = (float*)RA;                       // fc2 out, after A0 dead
    ushort_t* Anhi = (ushort_t*)(RA + 16515072);       // next-layer activations [16128x256]
    ushort_t* Anlo = (ushort_t*)(RA + 24772608);
    ushort_t* Thi  = (ushort_t*)RB;                    // fc1 out [16128 x <=512]
    ushort_t* Tlo  = (ushort_t*)(RB + 16515072);
    float*    agg  = (float*)RB;                       // aggregation, after T dead

    const dim3 blk(256);

    hipMemsetAsync(out, 0, (size_t)Nn * Cdim * 4, stream);
    hipMemsetAsync(deg, 0, Nn * 4, stream);

    // conversions
    pad_split<<<4096, blk, 0, stream>>>(x, Nn, Fdim, Mpad, 512, A0hi, A0lo);
    pad_split<<<1024, blk, 0, stream>>>(fc1w[0], 500, 500, 512, 512, w1hi[0], w1lo[0]);
    pad_split<<<512,  blk, 0, stream>>>(fc1w[1], 256, 256, 256, 256, w1hi[1], w1lo[1]);
    pad_split<<<512,  blk, 0, stream>>>(fc1w[2], 256, 256, 256, 256, w1hi[2], w1lo[2]);
    pad_split<<<512,  blk, 0, stream>>>(fc2w[0], 256, 500, 256, 512, w2hi[0], w2lo[0]);
    pad_split<<<512,  blk, 0, stream>>>(fc2w[1], 256, 256, 256, 256, w2hi[1], w2lo[1]);
    pad_split<<<512,  blk, 0, stream>>>(fc2w[2], 256, 256, 256, 256, w2hi[2], w2lo[2]);
    conv_wk<<<dim3((KPK + 255) / 256, Cdim), blk, 0, stream>>>(base_w, spline_w, wkhi, wklo);

    // CSR build (replaces per-layer atomic scatter)
    deg_hist<<<1024, blk, 0, stream>>>(ei, deg, E);
    scan16k<<<1, 1024, 0, stream>>>(deg, startA, cursor, dinv);
    csr_fill<<<1024, blk, 0, stream>>>(ei, cursor, csr, E);

    for (int l = 0; l < 3; l++) {
        const int Kp    = (l == 0) ? 512 : 256;   // fc1 K (padded)
        const int Npad1 = (l == 0) ? 512 : 256;   // fc1 Nout (padded) == fc2 K
        const int Nr1   = (l == 0) ? 500 : 256;
        const ushort_t* Ah_p = (l == 0) ? A0hi : Anhi;
        const ushort_t* Al_p = (l == 0) ? A0lo : Anlo;

        gemm_fc<0><<<dim3(126, Npad1 / 64), blk, 0, stream>>>(
            Ah_p, Al_p, w1hi[l], w1lo[l], fc1b[l], Nr1, Kp, Thi, Tlo, Npad1, nullptr);
        gemm_fc<1><<<dim3(126, 4), blk, 0, stream>>>(
            Thi, Tlo, w2hi[l], w2lo[l], fc2b[l], 256, Npad1, nullptr, nullptr, 0, zbuf);

        gather_agg<<<4000, blk, 0, stream>>>(zbuf, csr, startA, dinv, cb[l], agg);

        hipMemsetAsync(stats, 0, 512 * 4, stream);
        bn_stats<<<125, blk, 0, stream>>>(agg, stats);
        bn_final<<<1, blk, 0, stream>>>(stats, bg[l], bb[l], bnsc, bnsh);
        bn_apply_conv<<<4096, blk, 0, stream>>>(agg, bnsc, bnsh, hfeat, l * Hdim,
                                                Anhi, Anlo, (l < 2) ? 1 : 0);
    }

    kan_gemm<<<dim3(126, 5), blk, 0, stream>>>(x, hfeat, wkhi, wklo, out);
}